// Round 1
// baseline (337.431 us; speedup 1.0000x reference)
//
#include <hip/hip_runtime.h>

#define B_ 32
#define T_ 12
#define F_ 4
#define L_ 1024
#define H_ 64

// Hidden-state layout in workspace: h[L][B][H] (per-link column contiguous).
// One block per link. 256 threads: k = tid&63 (output column), bg = tid>>6,
// each thread owns 8 batch rows (b = bg*8 .. bg*8+7) at fixed k.
__global__ __launch_bounds__(256) void gru_step(
    const float* __restrict__ h_prev, float* __restrict__ h_next,
    const float* __restrict__ x,    const float* __restrict__ att,
    const float* __restrict__ w_rh, const float* __restrict__ b_rh,
    const float* __restrict__ w_ri, const float* __restrict__ b_ri,
    const float* __restrict__ w_uh, const float* __restrict__ b_uh,
    const float* __restrict__ w_ui, const float* __restrict__ b_ui,
    const float* __restrict__ w_nh, const float* __restrict__ b_nh,
    const float* __restrict__ w_ni, const float* __restrict__ b_ni,
    const float* __restrict__ w_fc, const float* __restrict__ b_fc,
    float* __restrict__ out, int t)
{
    const int l   = blockIdx.x;
    const int tid = threadIdx.x;
    const int k   = tid & 63;
    const int bg  = tid >> 6;
    const int b0  = bg * 8;

    __shared__ float hatt_t[H_][36];   // [h][b], padded 32->36 (bank spread + 16B-aligned float4 rows)
    __shared__ float wr_s[H_ * H_];    // 16 KB each, [h][k] row-major
    __shared__ float wu_s[H_ * H_];
    __shared__ float wn_s[H_ * H_];
    __shared__ float xt_s[B_][F_];

    // tridiagonal attention row l (values read from the actual matrix)
    const float a_c = att[l * L_ + l];
    const float a_l = (l > 0)      ? att[l * L_ + l - 1] : 0.0f;
    const float a_r = (l < L_ - 1) ? att[l * L_ + l + 1] : 0.0f;

    const float* hc = h_prev + (size_t)l * (B_ * H_);
    const float* hl = (l > 0)      ? hc - (B_ * H_) : hc;   // coeff 0 at boundary
    const float* hr = (l < L_ - 1) ? hc + (B_ * H_) : hc;

    // ---- stage hatt (transposed) : hatt_t[h][b] = a_c*h[l] + a_l*h[l-1] + a_r*h[l+1]
    for (int j = tid; j < B_ * H_; j += 256) {
        const int b = j >> 6, h = j & 63;
        hatt_t[h][b] = a_c * hc[j] + a_l * hl[j] + a_r * hr[j];
    }
    // ---- stage the three H x H gate weight matrices (coalesced float4)
    {
        const float4* wrg = (const float4*)(w_rh + (size_t)l * H_ * H_);
        const float4* wug = (const float4*)(w_uh + (size_t)l * H_ * H_);
        const float4* wng = (const float4*)(w_nh + (size_t)l * H_ * H_);
        float4* wrs = (float4*)wr_s;
        float4* wus = (float4*)wu_s;
        float4* wns = (float4*)wn_s;
        #pragma unroll
        for (int j = 0; j < 4; ++j) {
            const int idx = tid + j * 256;   // 1024 float4 = 4096 floats
            wrs[idx] = wrg[idx];
            wus[idx] = wug[idx];
            wns[idx] = wng[idx];
        }
    }
    if (tid < B_ * F_) {
        const int b = tid >> 2, f = tid & 3;
        xt_s[b][f] = x[(((size_t)b * T_ + t) * F_ + f) * L_ + l];
    }
    __syncthreads();

    // ---- accumulators (biases first)
    float accr[8], accz[8], accnh[8], accnx[8];
    {
        const float br  = b_rh[k * L_ + l] + b_ri[k * L_ + l];
        const float bz  = b_uh[k * L_ + l] + b_ui[k * L_ + l];
        const float bnh = b_nh[k * L_ + l];
        const float bnx = b_ni[k * L_ + l];
        #pragma unroll
        for (int i = 0; i < 8; ++i) {
            accr[i] = br; accz[i] = bz; accnh[i] = bnh; accnx[i] = bnx;
        }
    }
    // ---- input (F=4) contribution
    {
        const float* wri = w_ri + (size_t)l * F_ * H_;
        const float* wui = w_ui + (size_t)l * F_ * H_;
        const float* wni = w_ni + (size_t)l * F_ * H_;
        #pragma unroll
        for (int f = 0; f < F_; ++f) {
            const float wrv = wri[f * H_ + k];
            const float wuv = wui[f * H_ + k];
            const float wnv = wni[f * H_ + k];
            #pragma unroll
            for (int i = 0; i < 8; ++i) {
                const float xv = xt_s[b0 + i][f];
                accr[i]  += xv * wrv;
                accz[i]  += xv * wuv;
                accnx[i] += xv * wnv;
            }
        }
    }
    // ---- hidden (H=64) contribution: 24 FMAs per h from LDS
    #pragma unroll 8
    for (int h = 0; h < H_; ++h) {
        const float wrv = wr_s[h * H_ + k];
        const float wuv = wu_s[h * H_ + k];
        const float wnv = wn_s[h * H_ + k];
        const float4 ha0 = *(const float4*)&hatt_t[h][b0];
        const float4 ha1 = *(const float4*)&hatt_t[h][b0 + 4];
        const float a[8] = {ha0.x, ha0.y, ha0.z, ha0.w, ha1.x, ha1.y, ha1.z, ha1.w};
        #pragma unroll
        for (int i = 0; i < 8; ++i) {
            accr[i]  += a[i] * wrv;
            accz[i]  += a[i] * wuv;
            accnh[i] += a[i] * wnv;
        }
    }

    // ---- gates + state update
    float hv[8];
    #pragma unroll
    for (int i = 0; i < 8; ++i) {
        const int b = b0 + i;
        const float r = 1.0f / (1.0f + __expf(-accr[i]));
        const float z = 1.0f / (1.0f + __expf(-accz[i]));
        float nx = accnx[i] + r * accnh[i];
        nx = fminf(fmaxf(nx, -15.0f), 15.0f);            // avoid inf/inf
        const float e2 = __expf(2.0f * nx);
        const float n  = (e2 - 1.0f) / (e2 + 1.0f);      // tanh
        const float hp = hc[b * H_ + k];
        hv[i] = (1.0f - z) * n + z * hp;
    }

    if (t < T_ - 1) {
        float* hn = h_next + (size_t)l * (B_ * H_);
        #pragma unroll
        for (int i = 0; i < 8; ++i)
            hn[(b0 + i) * H_ + k] = hv[i];
    } else {
        // final step: fuse FC head  out[b, 0, l] = sum_k h[b,k]*w_fc[l,k,0] + b_fc[0,l]
        const float wf = w_fc[(size_t)l * H_ + k];       // O = 1
        #pragma unroll
        for (int i = 0; i < 8; ++i) {
            float v = hv[i] * wf;
            #pragma unroll
            for (int m = 32; m > 0; m >>= 1)
                v += __shfl_xor(v, m, 64);
            if (k == 0)
                out[(size_t)(b0 + i) * L_ + l] = v + b_fc[l];
        }
    }
}

extern "C" void kernel_launch(void* const* d_in, const int* in_sizes, int n_in,
                              void* d_out, int out_size, void* d_ws, size_t ws_size,
                              hipStream_t stream) {
    const float* x    = (const float*)d_in[0];
    const float* att  = (const float*)d_in[1];
    const float* w_rh = (const float*)d_in[2];
    const float* b_rh = (const float*)d_in[3];
    const float* w_ri = (const float*)d_in[4];
    const float* b_ri = (const float*)d_in[5];
    const float* w_uh = (const float*)d_in[6];
    const float* b_uh = (const float*)d_in[7];
    const float* w_ui = (const float*)d_in[8];
    const float* b_ui = (const float*)d_in[9];
    const float* w_nh = (const float*)d_in[10];
    const float* b_nh = (const float*)d_in[11];
    const float* w_ni = (const float*)d_in[12];
    const float* b_ni = (const float*)d_in[13];
    const float* w_fc = (const float*)d_in[14];
    const float* b_fc = (const float*)d_in[15];
    float* out = (float*)d_out;

    float* hA = (float*)d_ws;                    // h ping-pong: [L][B][H] f32, 8 MB each
    float* hB = hA + (size_t)L_ * B_ * H_;

    hipMemsetAsync(hA, 0, (size_t)L_ * B_ * H_ * sizeof(float), stream);  // h0 = 0

    const float* hp = hA;
    float*       hn = hB;
    for (int t = 0; t < T_; ++t) {
        gru_step<<<L_, 256, 0, stream>>>(hp, hn, x, att,
                                         w_rh, b_rh, w_ri, b_ri,
                                         w_uh, b_uh, w_ui, b_ui,
                                         w_nh, b_nh, w_ni, b_ni,
                                         w_fc, b_fc, out, t);
        float* tmp = (float*)hp; hp = hn; hn = tmp;
    }
}

// Round 2
// 265.671 us; speedup vs baseline: 1.2701x; 1.2701x over previous
//
#include <hip/hip_runtime.h>

#define B_ 32
#define T_ 12
#define F_ 4
#define L_ 1024
#define H_ 64

typedef _Float16 f16x8 __attribute__((ext_vector_type(8)));
typedef float f32x4 __attribute__((ext_vector_type(4)));

// XCD-chunked swizzle: blocks with bid%8==x handle links [x*128, x*128+128)
__device__ __forceinline__ int link_of_block(int bid) {
    return ((bid & 7) << 7) + (bid >> 3);
}

// ---------------------------------------------------------------------------
// Prepass: per link, transpose the three HxH gate weights into fp16
// Wt[l][g][kout][k] (contiguous k => 16B per-lane MFMA B-fragment loads),
// and repack the F=4 input-projection weights into WxT[l][g][kout][f] (float4).
// ---------------------------------------------------------------------------
__global__ __launch_bounds__(256) void prep_weights(
    const float* __restrict__ w_rh, const float* __restrict__ w_uh,
    const float* __restrict__ w_nh,
    const float* __restrict__ w_ri, const float* __restrict__ w_ui,
    const float* __restrict__ w_ni,
    _Float16* __restrict__ Wt, float* __restrict__ WxT)
{
    const int l   = link_of_block(blockIdx.x);
    const int tid = threadIdx.x;
    __shared__ float lt[H_][H_ + 1];

    const float* wh[3] = { w_rh, w_uh, w_nh };
    const float* wx[3] = { w_ri, w_ui, w_ni };

    for (int g = 0; g < 3; ++g) {
        // coalesced load of the 64x64 f32 tile into LDS
        const float4* src = (const float4*)(wh[g] + (size_t)l * H_ * H_);
        #pragma unroll
        for (int i = 0; i < 4; ++i) {
            const int e4 = tid + i * 256;          // float4 index 0..1023
            const float4 v = src[e4];
            const int e = e4 * 4;
            const int h = e >> 6, kout = e & 63;
            lt[h][kout]     = v.x;
            lt[h][kout + 1] = v.y;
            lt[h][kout + 2] = v.z;
            lt[h][kout + 3] = v.w;
        }
        __syncthreads();
        // transposed fp16 write: thread owns (kout = tid>>2, k-chunk of 16)
        {
            const int kout = tid >> 2, k0 = (tid & 3) * 16;
            _Float16 o[16];
            #pragma unroll
            for (int j = 0; j < 16; ++j) o[j] = (_Float16)lt[k0 + j][kout];
            _Float16* dst = Wt + (((size_t)l * 3 + g) * 64 + kout) * 64 + k0;
            ((f16x8*)dst)[0] = ((f16x8*)o)[0];
            ((f16x8*)dst)[1] = ((f16x8*)o)[1];
        }
        __syncthreads();
    }
    // input-projection weights: w_xi[l][f][kout] -> WxT[l][g][kout][f]
    {
        const int kout = tid >> 2, f = tid & 3;
        #pragma unroll
        for (int g = 0; g < 3; ++g)
            WxT[(((size_t)l * 3 + g) * 64 + kout) * 4 + f] =
                wx[g][(size_t)l * F_ * H_ + f * H_ + kout];
    }
}

// ---------------------------------------------------------------------------
// One GRU time step. One block per link, 4 waves; wave w owns kout slice
// [w*16, w*16+16). Hidden matmuls on MFMA fp16 (f32 accumulate), weights
// read directly from L2-resident Wt (no LDS staging, no main-path barrier).
// h layout in ws: [l][b][h] f32.
// ---------------------------------------------------------------------------
__global__ __launch_bounds__(256, 4) void gru_step(
    const float* __restrict__ hp, float* __restrict__ hn,
    const float* __restrict__ x,  const float* __restrict__ att,
    const _Float16* __restrict__ Wt, const float* __restrict__ WxT,
    const float* __restrict__ b_rh, const float* __restrict__ b_ri,
    const float* __restrict__ b_uh, const float* __restrict__ b_ui,
    const float* __restrict__ b_nh, const float* __restrict__ b_ni,
    const float* __restrict__ w_fc, const float* __restrict__ b_fc,
    float* __restrict__ out, int t)
{
    const int l    = link_of_block(blockIdx.x);
    const int tid  = threadIdx.x;
    const int wave = tid >> 6, lane = tid & 63;
    const int n    = lane & 15, kq = lane >> 4;
    const int kout = wave * 16 + n;

    __shared__ float4 xs[B_];        // x[b][0..3] for this link/time
    __shared__ float  psum[4][B_];   // FC head partials (t == T_-1 only)

    if (tid < B_ * F_) {
        const int b = tid >> 2, f = tid & 3;
        ((float*)xs)[tid] = x[(((size_t)b * T_ + t) * F_ + f) * L_ + l];
    }
    __syncthreads();

    f32x4 acc[3][2] = {};   // [gate r/z/nh][m-tile]

    if (t > 0) {
        const float a_c = att[l * L_ + l];
        const float a_l = (l > 0)      ? att[l * L_ + l - 1] : 0.0f;
        const float a_r = (l < L_ - 1) ? att[l * L_ + l + 1] : 0.0f;
        const float* hc = hp + (size_t)l * (B_ * H_);
        const float* hl = (l > 0)      ? hc - (B_ * H_) : hc;
        const float* hr = (l < L_ - 1) ? hc + (B_ * H_) : hc;

        // A fragments: hatt rows b = mt*16 + n, k-run = ks*32 + kq*8 .. +8
        f16x8 af[2][2];
        #pragma unroll
        for (int mt = 0; mt < 2; ++mt) {
            const int b = mt * 16 + n;
            #pragma unroll
            for (int ks = 0; ks < 2; ++ks) {
                const int off = b * H_ + ks * 32 + kq * 8;
                const float4 c0 = *(const float4*)(hc + off);
                const float4 c1 = *(const float4*)(hc + off + 4);
                const float4 l0 = *(const float4*)(hl + off);
                const float4 l1 = *(const float4*)(hl + off + 4);
                const float4 r0 = *(const float4*)(hr + off);
                const float4 r1 = *(const float4*)(hr + off + 4);
                f16x8 a;
                a[0] = (_Float16)(a_c * c0.x + a_l * l0.x + a_r * r0.x);
                a[1] = (_Float16)(a_c * c0.y + a_l * l0.y + a_r * r0.y);
                a[2] = (_Float16)(a_c * c0.z + a_l * l0.z + a_r * r0.z);
                a[3] = (_Float16)(a_c * c0.w + a_l * l0.w + a_r * r0.w);
                a[4] = (_Float16)(a_c * c1.x + a_l * l1.x + a_r * r1.x);
                a[5] = (_Float16)(a_c * c1.y + a_l * l1.y + a_r * r1.y);
                a[6] = (_Float16)(a_c * c1.z + a_l * l1.z + a_r * r1.z);
                a[7] = (_Float16)(a_c * c1.w + a_l * l1.w + a_r * r1.w);
                af[mt][ks] = a;
            }
        }
        // B fragments straight from global (L2-resident), 16B per lane
        const _Float16* wb = Wt + (size_t)l * 3 * 4096 + (size_t)kout * 64 + kq * 8;
        #pragma unroll
        for (int g = 0; g < 3; ++g) {
            #pragma unroll
            for (int ks = 0; ks < 2; ++ks) {
                const f16x8 bf = *(const f16x8*)(wb + g * 4096 + ks * 32);
                #pragma unroll
                for (int mt = 0; mt < 2; ++mt)
                    acc[g][mt] = __builtin_amdgcn_mfma_f32_16x16x32_f16(
                        af[mt][ks], bf, acc[g][mt], 0, 0, 0);
            }
        }
    }

    // ---- epilogue: biases + x-projection + gates (all f32)
    const float brh = b_rh[kout * L_ + l], bri = b_ri[kout * L_ + l];
    const float buh = b_uh[kout * L_ + l], bui = b_ui[kout * L_ + l];
    const float bnh = b_nh[kout * L_ + l], bni = b_ni[kout * L_ + l];
    const float4 wxr = *(const float4*)(WxT + (((size_t)l * 3 + 0) * 64 + kout) * 4);
    const float4 wxz = *(const float4*)(WxT + (((size_t)l * 3 + 1) * 64 + kout) * 4);
    const float4 wxn = *(const float4*)(WxT + (((size_t)l * 3 + 2) * 64 + kout) * 4);
    const float wfc = w_fc[(size_t)l * H_ + kout];

    float vout[2][4];
    #pragma unroll
    for (int mt = 0; mt < 2; ++mt) {
        #pragma unroll
        for (int r = 0; r < 4; ++r) {
            const int b = mt * 16 + kq * 4 + r;        // C row = (lane>>4)*4 + reg
            const float4 xb = xs[b];
            const float xr = xb.x*wxr.x + xb.y*wxr.y + xb.z*wxr.z + xb.w*wxr.w;
            const float xz = xb.x*wxz.x + xb.y*wxz.y + xb.z*wxz.z + xb.w*wxz.w;
            const float xn = xb.x*wxn.x + xb.y*wxn.y + xb.z*wxn.z + xb.w*wxn.w;
            const float pre_r = acc[0][mt][r] + brh + bri + xr;
            const float pre_z = acc[1][mt][r] + buh + bui + xz;
            const float rg = 1.0f / (1.0f + __expf(-pre_r));
            const float zg = 1.0f / (1.0f + __expf(-pre_z));
            float npre = xn + bni + rg * (acc[2][mt][r] + bnh);
            npre = fminf(fmaxf(npre, -15.0f), 15.0f);
            const float e2 = __expf(2.0f * npre);
            const float nn = (e2 - 1.0f) / (e2 + 1.0f);
            const float hpv = (t > 0) ? hp[(size_t)l * (B_*H_) + b * H_ + kout] : 0.0f;
            const float hv = (1.0f - zg) * nn + zg * hpv;
            if (t < T_ - 1)
                hn[(size_t)l * (B_*H_) + b * H_ + kout] = hv;
            else
                vout[mt][r] = hv * wfc;
        }
    }

    if (t == T_ - 1) {
        // FC head: reduce over kout. Sum over the 16 n-lanes, then over waves.
        #pragma unroll
        for (int mt = 0; mt < 2; ++mt) {
            #pragma unroll
            for (int r = 0; r < 4; ++r) {
                float v = vout[mt][r];
                v += __shfl_xor(v, 1, 64);
                v += __shfl_xor(v, 2, 64);
                v += __shfl_xor(v, 4, 64);
                v += __shfl_xor(v, 8, 64);
                if (n == 0) psum[wave][mt * 16 + kq * 4 + r] = v;
            }
        }
        __syncthreads();
        if (tid < B_) {
            const float s = psum[0][tid] + psum[1][tid] + psum[2][tid] + psum[3][tid];
            out[(size_t)tid * L_ + l] = s + b_fc[l];
        }
    }
}

extern "C" void kernel_launch(void* const* d_in, const int* in_sizes, int n_in,
                              void* d_out, int out_size, void* d_ws, size_t ws_size,
                              hipStream_t stream) {
    const float* x    = (const float*)d_in[0];
    const float* att  = (const float*)d_in[1];
    const float* w_rh = (const float*)d_in[2];
    const float* b_rh = (const float*)d_in[3];
    const float* w_ri = (const float*)d_in[4];
    const float* b_ri = (const float*)d_in[5];
    const float* w_uh = (const float*)d_in[6];
    const float* b_uh = (const float*)d_in[7];
    const float* w_ui = (const float*)d_in[8];
    const float* b_ui = (const float*)d_in[9];
    const float* w_nh = (const float*)d_in[10];
    const float* b_nh = (const float*)d_in[11];
    const float* w_ni = (const float*)d_in[12];
    const float* b_ni = (const float*)d_in[13];
    const float* w_fc = (const float*)d_in[14];
    const float* b_fc = (const float*)d_in[15];
    float* out = (float*)d_out;

    char* ws = (char*)d_ws;
    float*     hA  = (float*)ws;                       // 8 MB
    float*     hB  = (float*)(ws + (8u  << 20));       // 8 MB
    _Float16*  Wt  = (_Float16*)(ws + (16u << 20));    // 24 MB fp16 gate weights
    float*     WxT = (float*)(ws + (40u << 20));       // 3 MB input-proj weights

    prep_weights<<<L_, 256, 0, stream>>>(w_rh, w_uh, w_nh, w_ri, w_ui, w_ni, Wt, WxT);

    // ping-pong; t==0 reads nothing (h0 == 0 handled in-kernel, no memset)
    const float* hp = hB;
    float*       hn = hA;
    for (int t = 0; t < T_; ++t) {
        gru_step<<<L_, 256, 0, stream>>>(hp, hn, x, att, Wt, WxT,
                                         b_rh, b_ri, b_uh, b_ui, b_nh, b_ni,
                                         w_fc, b_fc, out, t);
        float* tmp = (float*)hp; hp = hn; hn = tmp;
    }
}